// Round 1
// baseline (57339.569 us; speedup 1.0000x reference)
//
#include <hip/hip_runtime.h>
#include <math.h>

#define BM 128
#define BN 128
#define BKK 16

__device__ __forceinline__ float gelu_f(float x) {
    float t = tanhf(0.7978845608028654f * (x + 0.044715f * x * x * x));
    return 0.5f * x * (1.0f + t);
}

// ---------------- GEMM: C[m,n] = sum_k A[m,k]*B[k,n] + bias[n] (+gelu) (+resid) ----------------
// REMAP: out row m -> (m/196)*197 + 1 + (m%196)  (patch-embed writes into SEQ layout)
template<int REMAP, int GELU, int RESID>
__global__ __launch_bounds__(256) void gemm_k(
    const float* __restrict__ A, const float* __restrict__ Bm,
    const float* __restrict__ bias, const float* __restrict__ resid,
    float* __restrict__ Cout, int M, int N, int K)
{
    __shared__ float As[BKK][BM];
    __shared__ float Bs[BKK][BN];
    int tid = threadIdx.x;
    int m0 = blockIdx.y * BM, n0 = blockIdx.x * BN;
    int ar = tid >> 1;              // 0..127
    int ac = (tid & 1) * 8;         // 0 or 8
    int br = tid >> 4;              // 0..15
    int bc = (tid & 15) * 8;        // 0..120
    int tx = tid & 15, ty = tid >> 4;
    float acc[8][8];
    #pragma unroll
    for (int i = 0; i < 8; i++)
        #pragma unroll
        for (int j = 0; j < 8; j++) acc[i][j] = 0.0f;

    for (int k0 = 0; k0 < K; k0 += BKK) {
        float4 a0, a1;
        if (m0 + ar < M) {
            const float* ap = A + (size_t)(m0 + ar) * K + k0 + ac;
            a0 = *(const float4*)ap;
            a1 = *(const float4*)(ap + 4);
        } else {
            a0 = make_float4(0.f, 0.f, 0.f, 0.f);
            a1 = a0;
        }
        const float* bp = Bm + (size_t)(k0 + br) * N + n0 + bc;
        float4 b0 = *(const float4*)bp;
        float4 b1 = *(const float4*)(bp + 4);
        __syncthreads();
        As[ac + 0][ar] = a0.x; As[ac + 1][ar] = a0.y; As[ac + 2][ar] = a0.z; As[ac + 3][ar] = a0.w;
        As[ac + 4][ar] = a1.x; As[ac + 5][ar] = a1.y; As[ac + 6][ar] = a1.z; As[ac + 7][ar] = a1.w;
        *(float4*)&Bs[br][bc] = b0;
        *(float4*)&Bs[br][bc + 4] = b1;
        __syncthreads();
        #pragma unroll
        for (int k = 0; k < BKK; ++k) {
            float a[8], b[8];
            *(float4*)(a)     = *(const float4*)&As[k][ty * 8];
            *(float4*)(a + 4) = *(const float4*)&As[k][ty * 8 + 4];
            *(float4*)(b)     = *(const float4*)&Bs[k][tx * 8];
            *(float4*)(b + 4) = *(const float4*)&Bs[k][tx * 8 + 4];
            #pragma unroll
            for (int i = 0; i < 8; i++)
                #pragma unroll
                for (int j = 0; j < 8; j++)
                    acc[i][j] += a[i] * b[j];
        }
    }

    #pragma unroll
    for (int i = 0; i < 8; i++) {
        int m = m0 + ty * 8 + i;
        if (m >= M) continue;
        size_t orow;
        if (REMAP) {
            int nimg = m / 196, p = m % 196;
            orow = (size_t)(nimg * 197 + 1 + p) * N;
        } else {
            orow = (size_t)m * N;
        }
        #pragma unroll
        for (int j4 = 0; j4 < 8; j4 += 4) {
            int n = n0 + tx * 8 + j4;
            float4 v;
            v.x = acc[i][j4 + 0] + bias[n + 0];
            v.y = acc[i][j4 + 1] + bias[n + 1];
            v.z = acc[i][j4 + 2] + bias[n + 2];
            v.w = acc[i][j4 + 3] + bias[n + 3];
            if (GELU) {
                v.x = gelu_f(v.x); v.y = gelu_f(v.y);
                v.z = gelu_f(v.z); v.w = gelu_f(v.w);
            }
            if (RESID) {
                float4 r = *(const float4*)&resid[orow + n];
                v.x += r.x; v.y += r.y; v.z += r.z; v.w += r.w;
            }
            *(float4*)&Cout[orow + n] = v;
        }
    }
}

// ---------------- im2col: images (64,3,224,224) -> patches (12544, 768) ----------------
__global__ __launch_bounds__(256) void im2col_k(const float* __restrict__ img, float* __restrict__ patches)
{
    int rp = blockIdx.x;            // n*196 + p
    int n = rp / 196, p = rp % 196;
    int pr = p / 14, pc = p % 14;
    int tid = threadIdx.x;
    for (int k = tid; k < 768; k += 256) {
        int c = k >> 8, rem = k & 255;
        int i = rem >> 4, j = rem & 15;
        patches[(size_t)rp * 768 + k] =
            img[(((size_t)n * 3 + c) * 224 + pr * 16 + i) * 224 + pc * 16 + j];
    }
}

// ---------------- cls token + positional embeddings ----------------
__global__ __launch_bounds__(256) void pos_k(const float* __restrict__ vcls, float* __restrict__ X)
{
    int r = blockIdx.x;             // 0 .. 64*197-1
    int srow = r % 197;
    int tid = threadIdx.x;
    const float c = -0.011992656734343933f; // -ln(10000)/768
    for (int j = tid; j < 768; j += 256) {
        float ang = (float)srow * expf(c * (float)j);
        float pe = (j & 1) ? cosf(ang) : sinf(ang);
        size_t idx = (size_t)r * 768 + j;
        if (srow == 0) X[idx] = vcls[j] + pe;
        else           X[idx] += pe;
    }
}

// ---------------- LayerNorm: H = (x-m)/sqrt(v+eps)*g + b, row-wise over 768 ----------------
__global__ __launch_bounds__(256) void ln_k(const float* __restrict__ X,
    const float* __restrict__ g, const float* __restrict__ b,
    float* __restrict__ Hout)
{
    int row = blockIdx.x;
    const float* x = X + (size_t)row * 768;
    int tid = threadIdx.x;
    float v0 = x[tid], v1 = x[tid + 256], v2 = x[tid + 512];
    __shared__ float red[256];
    red[tid] = v0 + v1 + v2;
    __syncthreads();
    for (int o = 128; o > 0; o >>= 1) { if (tid < o) red[tid] += red[tid + o]; __syncthreads(); }
    float mean = red[0] * (1.0f / 768.0f);
    __syncthreads();
    float d0 = v0 - mean, d1 = v1 - mean, d2 = v2 - mean;
    red[tid] = d0 * d0 + d1 * d1 + d2 * d2;
    __syncthreads();
    for (int o = 128; o > 0; o >>= 1) { if (tid < o) red[tid] += red[tid + o]; __syncthreads(); }
    float rstd = rsqrtf(red[0] * (1.0f / 768.0f) + 1e-5f);
    float* ho = Hout + (size_t)row * 768;
    ho[tid]       = d0 * rstd * g[tid]       + b[tid];
    ho[tid + 256] = d1 * rstd * g[tid + 256] + b[tid + 256];
    ho[tid + 512] = d2 * rstd * g[tid + 512] + b[tid + 512];
}

// ---------------- Attention: one wave per (n, h, s) query row ----------------
__global__ __launch_bounds__(256) void attn_k(const float* __restrict__ QKV, float* __restrict__ Y)
{
    __shared__ float sc[4][197];
    int tid = threadIdx.x;
    int lane = tid & 63, w = tid >> 6;
    int h = blockIdx.y, n = blockIdx.z;
    int s = blockIdx.x * 4 + w;
    bool valid = s < 197;
    int se = valid ? s : 196;
    const float* base = QKV + (size_t)n * 197 * 2304;
    int hc = h * 64 + lane;
    float q = base[(size_t)se * 2304 + hc];
    for (int t = 0; t < 197; t++) {
        float kv = base[(size_t)t * 2304 + 768 + hc];
        float p = q * kv;
        p += __shfl_xor(p, 32);
        p += __shfl_xor(p, 16);
        p += __shfl_xor(p, 8);
        p += __shfl_xor(p, 4);
        p += __shfl_xor(p, 2);
        p += __shfl_xor(p, 1);
        if (lane == 0) sc[w][t] = p * 0.125f;
    }
    __syncthreads();
    float m = -1e30f;
    for (int t = lane; t < 197; t += 64) m = fmaxf(m, sc[w][t]);
    for (int o = 32; o > 0; o >>= 1) m = fmaxf(m, __shfl_xor(m, o));
    float ssum = 0.0f;
    for (int t = lane; t < 197; t += 64) {
        float e = expf(sc[w][t] - m);
        sc[w][t] = e;
        ssum += e;
    }
    for (int o = 32; o > 0; o >>= 1) ssum += __shfl_xor(ssum, o);
    float inv = 1.0f / ssum;
    __syncthreads();
    float acc = 0.0f;
    for (int t = 0; t < 197; t++) {
        float vv = base[(size_t)t * 2304 + 1536 + hc];
        acc += sc[w][t] * vv;
    }
    if (valid) Y[((size_t)n * 197 + s) * 768 + hc] = acc * inv;
}

// ---------------- KAN head ----------------
__global__ __launch_bounds__(256) void sines_k(const float* __restrict__ X, float* __restrict__ sines)
{
    int n = blockIdx.x;
    const float* x = X + (size_t)n * 197 * 768;   // cls row (s=0)
    int tid = threadIdx.x;
    const float ph = 0.0040906154343610845f;      // pi/768
    for (int gi = tid; gi < 3072; gi += 256) {
        int g = gi / 768, i = gi % 768;
        sines[(size_t)n * 3072 + gi] = sinf(x[i] * (float)(g + 1) + (float)i * ph);
    }
}

__global__ __launch_bounds__(256) void kan_k(const float* __restrict__ sines,
    const float* __restrict__ amp, float* __restrict__ logits)
{
    int o = blockIdx.x;
    __shared__ float as_[3072];
    __shared__ float wred[4];
    int tid = threadIdx.x;
    for (int i = tid; i < 3072; i += 256) as_[i] = amp[(size_t)o * 3072 + i];
    __syncthreads();
    const float scale = 0.018042195912175804f;    // 1/sqrt(3072)
    int lane = tid & 63, w = tid >> 6;
    for (int n = 0; n < 64; n++) {
        float ssum = 0.0f;
        const float* sn = sines + (size_t)n * 3072;
        for (int i = tid; i < 3072; i += 256) ssum += sn[i] * as_[i];
        for (int off = 32; off > 0; off >>= 1) ssum += __shfl_xor(ssum, off);
        if (lane == 0) wred[w] = ssum;
        __syncthreads();
        if (tid == 0) logits[(size_t)n * 1000 + o] = (wred[0] + wred[1] + wred[2] + wred[3]) * scale;
        __syncthreads();
    }
}

__global__ __launch_bounds__(256) void smax_k(const float* __restrict__ logits, float* __restrict__ out)
{
    int n = blockIdx.x;
    const float* l = logits + (size_t)n * 1000;
    int tid = threadIdx.x;
    __shared__ float red[256];
    float m = -1e30f;
    for (int i = tid; i < 1000; i += 256) m = fmaxf(m, l[i]);
    red[tid] = m; __syncthreads();
    for (int o = 128; o > 0; o >>= 1) { if (tid < o) red[tid] = fmaxf(red[tid], red[tid + o]); __syncthreads(); }
    m = red[0]; __syncthreads();
    float s = 0.0f;
    for (int i = tid; i < 1000; i += 256) s += expf(l[i] - m);
    red[tid] = s; __syncthreads();
    for (int o = 128; o > 0; o >>= 1) { if (tid < o) red[tid] += red[tid + o]; __syncthreads(); }
    float inv = 1.0f / red[0];
    for (int i = tid; i < 1000; i += 256) out[(size_t)n * 1000 + i] = expf(l[i] - m) * inv;
}

extern "C" void kernel_launch(void* const* d_in, const int* in_sizes, int n_in,
                              void* d_out, int out_size, void* d_ws, size_t ws_size,
                              hipStream_t stream)
{
    const float* images  = (const float*)d_in[0];
    const float* v_class = (const float*)d_in[1];
    const float* W_map   = (const float*)d_in[2];
    const float* b_map   = (const float*)d_in[3];
    const float* ln1_s   = (const float*)d_in[4];
    const float* ln1_b   = (const float*)d_in[5];
    const float* Wqkv    = (const float*)d_in[6];
    const float* bqkv    = (const float*)d_in[7];
    const float* Wo      = (const float*)d_in[8];
    const float* bo      = (const float*)d_in[9];
    const float* ln2_s   = (const float*)d_in[10];
    const float* ln2_b   = (const float*)d_in[11];
    const float* Wm1     = (const float*)d_in[12];
    const float* bm1     = (const float*)d_in[13];
    const float* Wm2     = (const float*)d_in[14];
    const float* bm2     = (const float*)d_in[15];
    const float* kan     = (const float*)d_in[16];
    float* out = (float*)d_out;

    char* ws = (char*)d_ws;
    size_t off = 0;
    auto alloc = [&](size_t fl) {
        float* p = (float*)(ws + off);
        off += ((fl * 4 + 255) / 256) * 256;
        return p;
    };
    const int Mrows = 64 * 197;                 // 12608
    float* X     = alloc((size_t)Mrows * 768);
    float* Hb    = alloc((size_t)Mrows * 768);
    float* Yb    = alloc((size_t)Mrows * 768);
    float* BIG   = alloc((size_t)Mrows * 3072); // patches / QKV / MLP-mid (time-shared)
    float* sines = alloc(64 * 3072);
    float* logit = alloc(64 * 1000);

    // 1. patch embed
    im2col_k<<<12544, 256, 0, stream>>>(images, BIG);
    {
        dim3 g(768 / BN, (12544 + BM - 1) / BM);
        gemm_k<1, 0, 0><<<g, 256, 0, stream>>>(BIG, W_map, b_map, nullptr, X, 12544, 768, 768);
    }
    pos_k<<<64 * 197, 256, 0, stream>>>(v_class, X);

    dim3 gQKV(2304 / BN, (Mrows + BM - 1) / BM);
    dim3 gO  (768  / BN, (Mrows + BM - 1) / BM);
    dim3 gM1 (3072 / BN, (Mrows + BM - 1) / BM);
    dim3 gM2 (768  / BN, (Mrows + BM - 1) / BM);

    for (int b = 0; b < 12; b++) {
        ln_k<<<Mrows, 256, 0, stream>>>(X, ln1_s + b * 768, ln1_b + b * 768, Hb);
        gemm_k<0, 0, 0><<<gQKV, 256, 0, stream>>>(Hb, Wqkv + (size_t)b * 768 * 2304,
                                                  bqkv + b * 2304, nullptr, BIG, Mrows, 2304, 768);
        attn_k<<<dim3(50, 12, 64), 256, 0, stream>>>(BIG, Yb);
        gemm_k<0, 0, 1><<<gO, 256, 0, stream>>>(Yb, Wo + (size_t)b * 768 * 768,
                                                bo + b * 768, X, X, Mrows, 768, 768);
        ln_k<<<Mrows, 256, 0, stream>>>(X, ln2_s + b * 768, ln2_b + b * 768, Hb);
        gemm_k<0, 1, 0><<<gM1, 256, 0, stream>>>(Hb, Wm1 + (size_t)b * 768 * 3072,
                                                 bm1 + b * 3072, nullptr, BIG, Mrows, 3072, 768);
        gemm_k<0, 0, 1><<<gM2, 256, 0, stream>>>(BIG, Wm2 + (size_t)b * 3072 * 768,
                                                 bm2 + b * 768, X, X, Mrows, 768, 3072);
    }

    // 3. KAN head
    sines_k<<<64, 256, 0, stream>>>(X, sines);
    kan_k<<<1000, 256, 0, stream>>>(sines, kan, logit);
    smax_k<<<64, 256, 0, stream>>>(logit, out);
}

// Round 2
// 7933.675 us; speedup vs baseline: 7.2274x; 7.2274x over previous
//
#include <hip/hip_runtime.h>
#include <math.h>

typedef float f32x4 __attribute__((ext_vector_type(4)));
typedef __bf16 bf16x8 __attribute__((ext_vector_type(8)));
typedef unsigned int u32x4 __attribute__((ext_vector_type(4)));
typedef unsigned short u16;
typedef unsigned short u16x4 __attribute__((ext_vector_type(4)));

__device__ __forceinline__ u16 f2b(float x) {
    unsigned u = __builtin_bit_cast(unsigned, x);
    u += 0x7fff + ((u >> 16) & 1);
    return (u16)(u >> 16);
}

__device__ __forceinline__ bf16x8 ldb(const u16* p) {
    u32x4 v = *(const u32x4*)p;
    return __builtin_bit_cast(bf16x8, v);
}

__device__ __forceinline__ float gelu_f(float x) {
    float t = tanhf(0.7978845608028654f * (x + 0.044715f * x * x * x));
    return 0.5f * x * (1.0f + t);
}

// ---------------- weight transpose+convert: W (K x N) fp32 -> WT (N x K) bf16 ----------------
__global__ __launch_bounds__(256) void wtrans_k(const float* __restrict__ W, u16* __restrict__ WT,
                                                int K, int N)
{
    __shared__ float t[32][33];
    int kt = blockIdx.x, nt = blockIdx.y, b = blockIdx.z;
    const float* Wb = W + (size_t)b * K * N;
    u16* WTb = WT + (size_t)b * K * N;
    int r = threadIdx.x >> 3, c4 = (threadIdx.x & 7) * 4;
    float4 v = *(const float4*)(Wb + (size_t)(kt * 32 + r) * N + nt * 32 + c4);
    t[r][c4] = v.x; t[r][c4 + 1] = v.y; t[r][c4 + 2] = v.z; t[r][c4 + 3] = v.w;
    __syncthreads();
    u16x4 o;
    o.x = f2b(t[c4 + 0][r]); o.y = f2b(t[c4 + 1][r]);
    o.z = f2b(t[c4 + 2][r]); o.w = f2b(t[c4 + 3][r]);
    *(u16x4*)(WTb + (size_t)(nt * 32 + r) * K + kt * 32 + c4) = o;
}

// ---------------- MFMA GEMM: C[m,n] = sum_k A[m,k] * WT[n,k] (+bias) [+gelu] [+resid] ----------------
// A bf16 row-major M x K. WT bf16 row-major N x K. 128x128 block tile, BK=64, 4 waves 2x2.
template<int REMAP, int GELU, int RESID, int OUTBF16, int QKVMODE>
__global__ __launch_bounds__(256) void mgemm(
    const u16* __restrict__ A, const u16* __restrict__ Bw,
    const float* __restrict__ bias, const float* __restrict__ resid,
    float* __restrict__ Cf, u16* __restrict__ Cb, u16* __restrict__ VT,
    int M, int N, int K)
{
    __shared__ u16 As[128 * 72];
    __shared__ u16 Bs[128 * 72];
    const int tid = threadIdx.x;
    const int m0 = blockIdx.y * 128, n0 = blockIdx.x * 128;
    const int lane = tid & 63, wave = tid >> 6;
    const int wm = (wave & 1) * 64, wn = (wave >> 1) * 64;
    const int lrow = tid >> 3, lcol = (tid & 7) * 8;
    const int l15 = lane & 15, lq = lane >> 4;

    f32x4 acc[4][4];
    #pragma unroll
    for (int i = 0; i < 4; i++)
        #pragma unroll
        for (int j = 0; j < 4; j++) acc[i][j] = (f32x4){0.f, 0.f, 0.f, 0.f};

    for (int k0 = 0; k0 < K; k0 += 64) {
        u32x4 av[4], bv[4];
        #pragma unroll
        for (int i = 0; i < 4; i++) {
            int ar = lrow + i * 32;
            int am = m0 + ar; if (am >= M) am = M - 1;
            av[i] = *(const u32x4*)(A + (size_t)am * K + k0 + lcol);
            bv[i] = *(const u32x4*)(Bw + (size_t)(n0 + ar) * K + k0 + lcol);
        }
        __syncthreads();
        #pragma unroll
        for (int i = 0; i < 4; i++) {
            int ar = lrow + i * 32;
            *(u32x4*)(As + ar * 72 + lcol) = av[i];
            *(u32x4*)(Bs + ar * 72 + lcol) = bv[i];
        }
        __syncthreads();
        #pragma unroll
        for (int kk = 0; kk < 64; kk += 32) {
            bf16x8 af[4], bf[4];
            #pragma unroll
            for (int t = 0; t < 4; t++) {
                af[t] = ldb(As + (wm + t * 16 + l15) * 72 + kk + lq * 8);
                bf[t] = ldb(Bs + (wn + t * 16 + l15) * 72 + kk + lq * 8);
            }
            #pragma unroll
            for (int mt = 0; mt < 4; mt++)
                #pragma unroll
                for (int nt = 0; nt < 4; nt++)
                    acc[mt][nt] = __builtin_amdgcn_mfma_f32_16x16x32_bf16(af[mt], bf[nt], acc[mt][nt], 0, 0, 0);
        }
    }

    #pragma unroll
    for (int mt = 0; mt < 4; mt++) {
        #pragma unroll
        for (int nt = 0; nt < 4; nt++) {
            int n = n0 + wn + nt * 16 + l15;
            float bn = bias[n];
            #pragma unroll
            for (int r = 0; r < 4; r++) {
                int m = m0 + wm + mt * 16 + lq * 4 + r;
                if (m >= M) continue;
                float v = acc[mt][nt][r] + bn;
                if (GELU) v = gelu_f(v);
                if (QKVMODE && n >= 1536) {
                    int c = n - 1536, h = c >> 6, d = c & 63;
                    int ni = m / 197, s = m % 197;
                    VT[(((size_t)ni * 12 + h) * 64 + d) * 208 + s] = f2b(v);
                } else if (OUTBF16) {
                    Cb[(size_t)m * N + n] = f2b(v);
                } else {
                    size_t orow;
                    if (REMAP) {
                        int ni = m / 196, p = m % 196;
                        orow = (size_t)(ni * 197 + 1 + p) * N;
                    } else orow = (size_t)m * N;
                    float o = v;
                    if (RESID) o += resid[orow + n];
                    Cf[orow + n] = o;
                }
            }
        }
    }
}

// ---------------- im2col: images (64,3,224,224) fp32 -> patches (12544, 768) bf16 ----------------
__global__ __launch_bounds__(256) void im2col_k(const float* __restrict__ img, u16* __restrict__ patches)
{
    int rp = blockIdx.x;
    int n = rp / 196, p = rp % 196;
    int pr = p / 14, pc = p % 14;
    int tid = threadIdx.x;
    for (int k = tid; k < 768; k += 256) {
        int c = k >> 8, rem = k & 255;
        int i = rem >> 4, j = rem & 15;
        patches[(size_t)rp * 768 + k] =
            f2b(img[(((size_t)n * 3 + c) * 224 + pr * 16 + i) * 224 + pc * 16 + j]);
    }
}

// ---------------- cls token + positional embeddings (fp32 X) ----------------
__global__ __launch_bounds__(256) void pos_k(const float* __restrict__ vcls, float* __restrict__ X)
{
    int r = blockIdx.x;
    int srow = r % 197;
    int tid = threadIdx.x;
    const float c = -0.011992656734343933f; // -ln(10000)/768
    for (int j = tid; j < 768; j += 256) {
        float ang = (float)srow * expf(c * (float)j);
        float pe = (j & 1) ? cosf(ang) : sinf(ang);
        size_t idx = (size_t)r * 768 + j;
        if (srow == 0) X[idx] = vcls[j] + pe;
        else           X[idx] += pe;
    }
}

// ---------------- LayerNorm: fp32 X -> bf16 H ----------------
__global__ __launch_bounds__(256) void ln_k(const float* __restrict__ X,
    const float* __restrict__ g, const float* __restrict__ b,
    u16* __restrict__ Hout)
{
    int row = blockIdx.x;
    const float* x = X + (size_t)row * 768;
    int tid = threadIdx.x;
    float v0 = x[tid], v1 = x[tid + 256], v2 = x[tid + 512];
    __shared__ float red[256];
    red[tid] = v0 + v1 + v2;
    __syncthreads();
    for (int o = 128; o > 0; o >>= 1) { if (tid < o) red[tid] += red[tid + o]; __syncthreads(); }
    float mean = red[0] * (1.0f / 768.0f);
    __syncthreads();
    float d0 = v0 - mean, d1 = v1 - mean, d2 = v2 - mean;
    red[tid] = d0 * d0 + d1 * d1 + d2 * d2;
    __syncthreads();
    for (int o = 128; o > 0; o >>= 1) { if (tid < o) red[tid] += red[tid + o]; __syncthreads(); }
    float rstd = rsqrtf(red[0] * (1.0f / 768.0f) + 1e-5f);
    u16* ho = Hout + (size_t)row * 768;
    ho[tid]       = f2b(d0 * rstd * g[tid]       + b[tid]);
    ho[tid + 256] = f2b(d1 * rstd * g[tid + 256] + b[tid + 256]);
    ho[tid + 512] = f2b(d2 * rstd * g[tid + 512] + b[tid + 512]);
}

// ---------------- MFMA attention: one block per (h, n) ----------------
// QKV bf16 [12608][2304] (Q cols 0..767, K cols 768..1535). VT bf16 [n][h][64][208].
// Y bf16 [12608][768].
__global__ __launch_bounds__(256) void attn2_k(const u16* __restrict__ QKV,
                                               const u16* __restrict__ VT,
                                               u16* __restrict__ Y)
{
    __shared__ u16 Ks[208 * 72];
    __shared__ u16 Vs[64 * 232];
    __shared__ u16 Ps[4][16 * 224];
    int tid = threadIdx.x, lane = tid & 63, w = tid >> 6;
    int h = blockIdx.x, n = blockIdx.y;
    const int l15 = lane & 15, lq = lane >> 4;
    const u16* base = QKV + (size_t)n * 197 * 2304;

    // stage K[t][d] (zero-padded t>=197)
    for (int c = tid; c < 208 * 8; c += 256) {
        int t = c >> 3, d8 = (c & 7) * 8;
        u32x4 v = (u32x4){0u, 0u, 0u, 0u};
        if (t < 197) v = *(const u32x4*)(base + (size_t)t * 2304 + 768 + h * 64 + d8);
        *(u32x4*)(Ks + t * 72 + d8) = v;
    }
    // stage Vt[d][t] from VT (t>=208 zero)
    const u16* vtb = VT + ((size_t)n * 12 + h) * 64 * 208;
    for (int c = tid; c < 64 * 29; c += 256) {
        int d = c / 29, t8 = (c % 29) * 8;
        u32x4 v = (u32x4){0u, 0u, 0u, 0u};
        if (t8 < 208) v = *(const u32x4*)(vtb + (size_t)d * 208 + t8);
        *(u32x4*)(Vs + d * 232 + t8) = v;
    }
    // zero P tail cols 208..223 (per-wave)
    for (int i = lane; i < 256; i += 64) {
        int rr = i >> 4, cc = i & 15;
        Ps[w][rr * 224 + 208 + cc] = 0;
    }
    __syncthreads();

    for (int s0i = w; s0i < 13; s0i += 4) {
        int s0 = s0i * 16;
        // Q A-fragments (direct from global, clamp row)
        int qs = s0 + l15; if (qs > 196) qs = 196;
        const u16* qp = base + (size_t)qs * 2304 + h * 64 + lq * 8;
        bf16x8 qa0 = ldb(qp);
        bf16x8 qa1 = ldb(qp + 32);

        f32x4 sc[13];
        #pragma unroll
        for (int nt = 0; nt < 13; nt++) sc[nt] = (f32x4){0.f, 0.f, 0.f, 0.f};
        #pragma unroll
        for (int nt = 0; nt < 13; nt++) {
            bf16x8 kb0 = ldb(Ks + (nt * 16 + l15) * 72 + lq * 8);
            bf16x8 kb1 = ldb(Ks + (nt * 16 + l15) * 72 + 32 + lq * 8);
            sc[nt] = __builtin_amdgcn_mfma_f32_16x16x32_bf16(qa0, kb0, sc[nt], 0, 0, 0);
            sc[nt] = __builtin_amdgcn_mfma_f32_16x16x32_bf16(qa1, kb1, sc[nt], 0, 0, 0);
        }
        // softmax per row r (rows live in 16-lane groups; cols = nt*16 + l15)
        #pragma unroll
        for (int r = 0; r < 4; r++) {
            float mx = -1e30f;
            #pragma unroll
            for (int nt = 0; nt < 13; nt++) {
                float v = sc[nt][r] * 0.125f;
                if (nt == 12 && l15 >= 5) v = -1e30f;   // mask t >= 197
                sc[nt][r] = v;
                mx = fmaxf(mx, v);
            }
            mx = fmaxf(mx, __shfl_xor(mx, 1));
            mx = fmaxf(mx, __shfl_xor(mx, 2));
            mx = fmaxf(mx, __shfl_xor(mx, 4));
            mx = fmaxf(mx, __shfl_xor(mx, 8));
            float ssum = 0.f;
            #pragma unroll
            for (int nt = 0; nt < 13; nt++) {
                float e = expf(sc[nt][r] - mx);
                sc[nt][r] = e;
                ssum += e;
            }
            ssum += __shfl_xor(ssum, 1);
            ssum += __shfl_xor(ssum, 2);
            ssum += __shfl_xor(ssum, 4);
            ssum += __shfl_xor(ssum, 8);
            float inv = 1.0f / ssum;
            #pragma unroll
            for (int nt = 0; nt < 13; nt++)
                Ps[w][(lq * 4 + r) * 224 + nt * 16 + l15] = f2b(sc[nt][r] * inv);
        }
        // PV: y[s][d] = sum_t P[s][t] V[t][d]
        f32x4 ya[4];
        #pragma unroll
        for (int i = 0; i < 4; i++) ya[i] = (f32x4){0.f, 0.f, 0.f, 0.f};
        #pragma unroll
        for (int ks = 0; ks < 7; ks++) {
            bf16x8 pa = ldb(&Ps[w][l15 * 224 + ks * 32 + lq * 8]);
            #pragma unroll
            for (int nt2 = 0; nt2 < 4; nt2++) {
                bf16x8 vb = ldb(Vs + (nt2 * 16 + l15) * 232 + ks * 32 + lq * 8);
                ya[nt2] = __builtin_amdgcn_mfma_f32_16x16x32_bf16(pa, vb, ya[nt2], 0, 0, 0);
            }
        }
        #pragma unroll
        for (int nt2 = 0; nt2 < 4; nt2++) {
            #pragma unroll
            for (int r = 0; r < 4; r++) {
                int s = s0 + lq * 4 + r;
                if (s < 197) {
                    int d = nt2 * 16 + l15;
                    Y[((size_t)n * 197 + s) * 768 + h * 64 + d] = f2b(ya[nt2][r]);
                }
            }
        }
    }
}

// ---------------- KAN head (fp32) ----------------
__global__ __launch_bounds__(256) void sines_k(const float* __restrict__ X, float* __restrict__ sines)
{
    int n = blockIdx.x;
    const float* x = X + (size_t)n * 197 * 768;
    int tid = threadIdx.x;
    const float ph = 0.0040906154343610845f; // pi/768
    for (int gi = tid; gi < 3072; gi += 256) {
        int g = gi / 768, i = gi % 768;
        sines[(size_t)n * 3072 + gi] = sinf(x[i] * (float)(g + 1) + (float)i * ph);
    }
}

__global__ __launch_bounds__(256) void kan_k(const float* __restrict__ sines,
    const float* __restrict__ amp, float* __restrict__ logits)
{
    int o = blockIdx.x;
    __shared__ float as_[3072];
    __shared__ float wred[4];
    int tid = threadIdx.x;
    for (int i = tid; i < 3072; i += 256) as_[i] = amp[(size_t)o * 3072 + i];
    __syncthreads();
    const float scale = 0.018042195912175804f; // 1/sqrt(3072)
    int lane = tid & 63, w = tid >> 6;
    for (int n = 0; n < 64; n++) {
        float ssum = 0.0f;
        const float* sn = sines + (size_t)n * 3072;
        for (int i = tid; i < 3072; i += 256) ssum += sn[i] * as_[i];
        for (int off = 32; off > 0; off >>= 1) ssum += __shfl_xor(ssum, off);
        if (lane == 0) wred[w] = ssum;
        __syncthreads();
        if (tid == 0) logits[(size_t)n * 1000 + o] = (wred[0] + wred[1] + wred[2] + wred[3]) * scale;
        __syncthreads();
    }
}

__global__ __launch_bounds__(256) void smax_k(const float* __restrict__ logits, float* __restrict__ out)
{
    int n = blockIdx.x;
    const float* l = logits + (size_t)n * 1000;
    int tid = threadIdx.x;
    __shared__ float red[256];
    float m = -1e30f;
    for (int i = tid; i < 1000; i += 256) m = fmaxf(m, l[i]);
    red[tid] = m; __syncthreads();
    for (int o = 128; o > 0; o >>= 1) { if (tid < o) red[tid] = fmaxf(red[tid], red[tid + o]); __syncthreads(); }
    m = red[0]; __syncthreads();
    float s = 0.0f;
    for (int i = tid; i < 1000; i += 256) s += expf(l[i] - m);
    red[tid] = s; __syncthreads();
    for (int o = 128; o > 0; o >>= 1) { if (tid < o) red[tid] += red[tid + o]; __syncthreads(); }
    float inv = 1.0f / red[0];
    for (int i = tid; i < 1000; i += 256) out[(size_t)n * 1000 + i] = expf(l[i] - m) * inv;
}

extern "C" void kernel_launch(void* const* d_in, const int* in_sizes, int n_in,
                              void* d_out, int out_size, void* d_ws, size_t ws_size,
                              hipStream_t stream)
{
    const float* images  = (const float*)d_in[0];
    const float* v_class = (const float*)d_in[1];
    const float* W_map   = (const float*)d_in[2];
    const float* b_map   = (const float*)d_in[3];
    const float* ln1_s   = (const float*)d_in[4];
    const float* ln1_b   = (const float*)d_in[5];
    const float* Wqkv    = (const float*)d_in[6];
    const float* bqkv    = (const float*)d_in[7];
    const float* Wo      = (const float*)d_in[8];
    const float* bo      = (const float*)d_in[9];
    const float* ln2_s   = (const float*)d_in[10];
    const float* ln2_b   = (const float*)d_in[11];
    const float* Wm1     = (const float*)d_in[12];
    const float* bm1     = (const float*)d_in[13];
    const float* Wm2     = (const float*)d_in[14];
    const float* bm2     = (const float*)d_in[15];
    const float* kan     = (const float*)d_in[16];
    float* out = (float*)d_out;

    char* ws = (char*)d_ws;
    size_t off = 0;
    auto alloc = [&](size_t bytes) {
        void* p = ws + off;
        off += (bytes + 255) & ~(size_t)255;
        return p;
    };
    const int Mrows = 64 * 197; // 12608

    float* X    = (float*)alloc((size_t)Mrows * 768 * 4);
    u16* Hb     = (u16*)  alloc((size_t)Mrows * 768 * 2);
    u16* Yb     = (u16*)  alloc((size_t)Mrows * 768 * 2);
    u16* BIG    = (u16*)  alloc((size_t)Mrows * 3072 * 2); // patches / QKV / MLP-mid
    u16* VT     = (u16*)  alloc((size_t)64 * 12 * 64 * 208 * 2);
    u16* WmapT  = (u16*)  alloc((size_t)768 * 768 * 2);
    u16* WqkvT  = (u16*)  alloc((size_t)12 * 768 * 2304 * 2);
    u16* WoT    = (u16*)  alloc((size_t)12 * 768 * 768 * 2);
    u16* Wm1T   = (u16*)  alloc((size_t)12 * 768 * 3072 * 2);
    u16* Wm2T   = (u16*)  alloc((size_t)12 * 3072 * 768 * 2);
    float* sines= (float*)alloc((size_t)64 * 3072 * 4);
    float* logit= (float*)alloc((size_t)64 * 1000 * 4);

    // weight transpose+convert
    wtrans_k<<<dim3(768 / 32, 768 / 32, 1),  256, 0, stream>>>(W_map, WmapT, 768, 768);
    wtrans_k<<<dim3(768 / 32, 2304 / 32, 12), 256, 0, stream>>>(Wqkv, WqkvT, 768, 2304);
    wtrans_k<<<dim3(768 / 32, 768 / 32, 12), 256, 0, stream>>>(Wo, WoT, 768, 768);
    wtrans_k<<<dim3(768 / 32, 3072 / 32, 12), 256, 0, stream>>>(Wm1, Wm1T, 768, 3072);
    wtrans_k<<<dim3(3072 / 32, 768 / 32, 12), 256, 0, stream>>>(Wm2, Wm2T, 3072, 768);

    // patch embed
    im2col_k<<<12544, 256, 0, stream>>>(images, BIG);
    mgemm<1, 0, 0, 0, 0><<<dim3(6, 98), 256, 0, stream>>>(
        BIG, WmapT, b_map, nullptr, X, nullptr, nullptr, 12544, 768, 768);
    pos_k<<<64 * 197, 256, 0, stream>>>(v_class, X);

    const int MT = (Mrows + 127) / 128; // 99
    for (int b = 0; b < 12; b++) {
        ln_k<<<Mrows, 256, 0, stream>>>(X, ln1_s + b * 768, ln1_b + b * 768, Hb);
        mgemm<0, 0, 0, 1, 1><<<dim3(18, MT), 256, 0, stream>>>(
            Hb, WqkvT + (size_t)b * 768 * 2304, bqkv + b * 2304, nullptr,
            nullptr, BIG, VT, Mrows, 2304, 768);
        attn2_k<<<dim3(12, 64), 256, 0, stream>>>(BIG, VT, Yb);
        mgemm<0, 0, 1, 0, 0><<<dim3(6, MT), 256, 0, stream>>>(
            Yb, WoT + (size_t)b * 768 * 768, bo + b * 768, X,
            X, nullptr, nullptr, Mrows, 768, 768);
        ln_k<<<Mrows, 256, 0, stream>>>(X, ln2_s + b * 768, ln2_b + b * 768, Hb);
        mgemm<0, 1, 0, 1, 0><<<dim3(24, MT), 256, 0, stream>>>(
            Hb, Wm1T + (size_t)b * 768 * 3072, bm1 + b * 3072, nullptr,
            nullptr, BIG, nullptr, Mrows, 3072, 768);
        mgemm<0, 0, 1, 0, 0><<<dim3(6, MT), 256, 0, stream>>>(
            BIG, Wm2T + (size_t)b * 3072 * 768, bm2 + b * 768, X,
            X, nullptr, nullptr, Mrows, 768, 3072);
    }

    sines_k<<<64, 256, 0, stream>>>(X, sines);
    kan_k<<<1000, 256, 0, stream>>>(sines, kan, logit);
    smax_k<<<64, 256, 0, stream>>>(logit, out);
}